// Round 4
// baseline (229.418 us; speedup 1.0000x reference)
//
#include <hip/hip_runtime.h>

#define SL  2048
#define BSZ 32
#define DIM 1024
#define NH  16
#define HD  64

typedef __attribute__((ext_vector_type(4))) float f32x4;
typedef __attribute__((ext_vector_type(8))) short s16x8;

static __device__ __forceinline__ short f2bf(float f) {
    union { float f; unsigned u; } v; v.f = f;
    unsigned r = (v.u + 0x7fffu + ((v.u >> 16) & 1u)) >> 16;  // RNE
    return (short)r;
}

// Fused: qp_slice[i] = query[b].Wq[h*64+i]  (i<64), then
// u[b][h][j] = 0.125 * sum_i qp_slice[i] * Wk[h*64+i][j]  (bf16)
// grid 512 = (b,h); block 256.
__global__ __launch_bounds__(256) void k_qu(const float* __restrict__ query,
                                            const float* __restrict__ Wq,
                                            const float* __restrict__ Wk,
                                            short* __restrict__ u) {
    int b = blockIdx.x & 31;
    int h = blockIdx.x >> 5;
    int t = threadIdx.x;
    __shared__ float red[256];
    __shared__ float sq[HD];
    {   // stage 1: 4 threads per i (k-quarters)
        int i  = t >> 2;
        int kq = t & 3;
        const float* q = query + (size_t)b * DIM + kq * 256;
        const float* w = Wq + (size_t)(h * HD + i) * DIM + kq * 256;
        f32x4 acc = {0.f, 0.f, 0.f, 0.f};
#pragma unroll 4
        for (int k = 0; k < 256; k += 4)
            acc += *(const f32x4*)(q + k) * *(const f32x4*)(w + k);
        red[t] = acc[0] + acc[1] + acc[2] + acc[3];
    }
    __syncthreads();
    if (t < HD) sq[t] = (red[t*4] + red[t*4+1] + red[t*4+2] + red[t*4+3]) * 0.125f;
    __syncthreads();
    // stage 2: each thread owns 4 j columns
    f32x4 acc = {0.f, 0.f, 0.f, 0.f};
    const float* wk = Wk + (size_t)(h * HD) * DIM;
#pragma unroll 8
    for (int i = 0; i < HD; ++i) {
        float s = sq[i];
        const float* row = wk + (size_t)i * DIM;
        acc[0] += s * row[t];
        acc[1] += s * row[t + 256];
        acc[2] += s * row[t + 512];
        acc[3] += s * row[t + 768];
    }
    short* ub = u + ((size_t)(b * NH + h)) * DIM;
    ub[t]       = f2bf(acc[0]);
    ub[t + 256] = f2bf(acc[1]);
    ub[t + 512] = f2bf(acc[2]);
    ub[t + 768] = f2bf(acc[3]);
}

// dot[b][s][h] = keys[s,b,:].u[b,h,:]; also per-block LSE partials (m,l) per h.
// grid 1024 = 32 b x 32 s-tiles(64); block 256 = 4 waves x 16 rows.
__global__ __launch_bounds__(256, 4) void k_dot(const float* __restrict__ keys,
                                                const short* __restrict__ u,
                                                float* __restrict__ dot,
                                                float2* __restrict__ part) {
    int b  = blockIdx.x & 31;
    int st = blockIdx.x >> 5;
    int s0 = st * 64;
    __shared__ short ulds[NH][DIM + 8];
    {
        const uint4* src = (const uint4*)(u + (size_t)b * NH * DIM);
        for (int idx = threadIdx.x; idx < NH * DIM / 8; idx += 256) {
            int row = idx >> 7;
            int col = (idx & 127) * 8;
            *(uint4*)&ulds[row][col] = src[idx];
        }
    }
    __syncthreads();
    int lane = threadIdx.x & 63;
    int wave = threadIdx.x >> 6;
    int lrow = lane & 15;
    int kgrp = lane >> 4;
    f32x4 acc = {0.f, 0.f, 0.f, 0.f};
    const float* ka = keys + ((size_t)(s0 + wave * 16 + lrow) * BSZ + b) * DIM;
#pragma unroll 4
    for (int k0 = 0; k0 < DIM; k0 += 32) {
        int kj = k0 + kgrp * 8;
        s16x8 bf = *(const s16x8*)&ulds[lrow][kj];
        f32x4 a0 = *(const f32x4*)(ka + kj);
        f32x4 a1 = *(const f32x4*)(ka + kj + 4);
        s16x8 af;
        af[0]=f2bf(a0[0]); af[1]=f2bf(a0[1]); af[2]=f2bf(a0[2]); af[3]=f2bf(a0[3]);
        af[4]=f2bf(a1[0]); af[5]=f2bf(a1[1]); af[6]=f2bf(a1[2]); af[7]=f2bf(a1[3]);
        acc = __builtin_amdgcn_mfma_f32_16x16x32_bf16(af, bf, acc, 0, 0, 0);
    }
    // write dot (C layout: col(h)=lane&15, row=(lane>>4)*4+r)
    size_t obase = ((size_t)b * SL + (s0 + wave * 16 + kgrp * 4)) * NH + lrow;
#pragma unroll
    for (int r = 0; r < 4; ++r)
        dot[obase + (size_t)r * NH] = acc[r];

    // partial LSE over this block's 64 s rows, per h=lrow
    __shared__ float mred[4][16], lred[4][16];
    float m = fmaxf(fmaxf(acc[0], acc[1]), fmaxf(acc[2], acc[3]));
    m = fmaxf(m, __shfl_xor(m, 16));
    m = fmaxf(m, __shfl_xor(m, 32));
    if (lane < 16) mred[wave][lrow] = m;
    __syncthreads();
    float mb = fmaxf(fmaxf(mred[0][lrow], mred[1][lrow]),
                     fmaxf(mred[2][lrow], mred[3][lrow]));
    float l = __expf(acc[0]-mb) + __expf(acc[1]-mb) + __expf(acc[2]-mb) + __expf(acc[3]-mb);
    l += __shfl_xor(l, 16);
    l += __shfl_xor(l, 32);
    if (lane < 16) lred[wave][lrow] = l;
    __syncthreads();
    int t = threadIdx.x;
    if (t < 16) {
        float mbb = fmaxf(fmaxf(mred[0][t], mred[1][t]), fmaxf(mred[2][t], mred[3][t]));
        float lb  = lred[0][t] + lred[1][t] + lred[2][t] + lred[3][t];
        part[((size_t)b * 32 + st) * 16 + t] = make_float2(mbb, lb);
    }
}

// zp[sh][b][h][j] = sum_{s in half} dot*v  -  T[b][h] * sum_{s in half} v
// T combined in-prologue from k_dot partials. grid 1024 = 32 b x 16 jc x 2 sh.
__global__ __launch_bounds__(256, 4) void k_z(const float* __restrict__ values,
                                              const float* __restrict__ w,
                                              const float2* __restrict__ part,
                                              float* __restrict__ z) {
    int x  = blockIdx.x;
    int b  = x & 31;
    int jc = (x >> 5) & 15;
    int sh = x >> 9;
    int t  = threadIdx.x;
    int ssub = t >> 4;
    int jq = t & 15;
    int j = jc * 64 + jq * 4;
    int wv = __builtin_amdgcn_readfirstlane(t >> 6);
    int lane = t & 63;

    __shared__ float wlds[128 * 16];        // 8 KB
    __shared__ float Tl[16];
    __shared__ f32x4 redW[4][16][16];       // 16 KB
    __shared__ f32x4 redV[4][16];           // 1 KB

    // combine LSE partials -> T[h]
    if (t < 16) {
        const float2* pb = part + (size_t)b * 32 * 16 + t;
        float M = -1e30f;
#pragma unroll
        for (int i = 0; i < 32; ++i) M = fmaxf(M, pb[i * 16].x);
        float L = 0.f;
#pragma unroll
        for (int i = 0; i < 32; ++i) { float2 p = pb[i * 16]; L += p.y * __expf(p.x - M); }
        Tl[t] = M + __logf(L);
    }

    f32x4 acc[NH];
#pragma unroll
    for (int h = 0; h < NH; ++h) acc[h] = (f32x4){0.f,0.f,0.f,0.f};
    f32x4 accV = {0.f,0.f,0.f,0.f};

    const float* vbase = values + (size_t)b * DIM + j;
    const float* wbase = w + ((size_t)b * SL + sh * 1024) * NH;

    // T14 async-stage: prefetch phase tile into regs, write after barrier
    const f32x4* src = (const f32x4*)wbase;
    f32x4 w0 = src[t], w1 = src[t + 256];

    for (int ph = 0; ph < 8; ++ph) {
        __syncthreads();                     // prev-phase readers done
        f32x4* dst = (f32x4*)wlds;
        dst[t]       = w0;
        dst[t + 256] = w1;
        __syncthreads();
        if (ph + 1 < 8) {
            src += 512;
            w0 = src[t];
            w1 = src[t + 256];
        }
        int sbase = sh * 1024 + ph * 128;
#pragma unroll 4
        for (int it = 0; it < 8; ++it) {
            int s_loc = it * 16 + ssub;
            f32x4 v = *(const f32x4*)(vbase + (size_t)(sbase + s_loc) * (BSZ * DIM));
            const f32x4* wr = (const f32x4*)(wlds + s_loc * 16);
            f32x4 wv0 = wr[0], wv1 = wr[1], wv2 = wr[2], wv3 = wr[3];
            acc[0]  += v * wv0[0]; acc[1]  += v * wv0[1]; acc[2]  += v * wv0[2]; acc[3]  += v * wv0[3];
            acc[4]  += v * wv1[0]; acc[5]  += v * wv1[1]; acc[6]  += v * wv1[2]; acc[7]  += v * wv1[3];
            acc[8]  += v * wv2[0]; acc[9]  += v * wv2[1]; acc[10] += v * wv2[2]; acc[11] += v * wv2[3];
            acc[12] += v * wv3[0]; acc[13] += v * wv3[1]; acc[14] += v * wv3[2]; acc[15] += v * wv3[3];
            accV += v;
        }
    }

    // reduce across ssub within wave (lanes 16, 32 apart)
#pragma unroll
    for (int h = 0; h < NH; ++h) {
#pragma unroll
        for (int e = 0; e < 4; ++e) {
            float x0 = acc[h][e];
            x0 += __shfl_xor(x0, 16);
            x0 += __shfl_xor(x0, 32);
            acc[h][e] = x0;
        }
    }
#pragma unroll
    for (int e = 0; e < 4; ++e) {
        float x0 = accV[e];
        x0 += __shfl_xor(x0, 16);
        x0 += __shfl_xor(x0, 32);
        accV[e] = x0;
    }
    if (lane < 16) {
#pragma unroll
        for (int h = 0; h < NH; ++h) redW[wv][h][lane] = acc[h];
        redV[wv][lane] = accV;
    }
    __syncthreads();
    int h2 = t >> 4, q = t & 15;
    f32x4 sumW = redW[0][h2][q] + redW[1][h2][q] + redW[2][h2][q] + redW[3][h2][q];
    f32x4 sumV = redV[0][q] + redV[1][q] + redV[2][q] + redV[3][q];
    float Th = Tl[h2];
    f32x4 zv = sumW - Th * sumV;
    float* zp = z + (size_t)sh * (BSZ * NH * DIM);
    *(f32x4*)(zp + ((size_t)(b * NH + h2)) * DIM + jc * 64 + q * 4) = zv;
}

// O[b][o] = dot(A_row(b,o) [+A2_row], W[o][:])
template<bool DUAL>
__global__ __launch_bounds__(256) void k_gemm(const float* __restrict__ A,
                                              const float* __restrict__ A2,
                                              const float* __restrict__ W,
                                              float* __restrict__ O,
                                              int rmul, int hsel) {
    int oc = blockIdx.x & 15;
    int b  = blockIdx.x >> 4;
    int wv = __builtin_amdgcn_readfirstlane(threadIdx.x >> 6);
    int lane = threadIdx.x & 63;
    int o = oc * 64 + lane;
    int row = b * rmul + (hsel ? oc : 0);
    const float* arow  = A + (size_t)row * DIM + wv * 256;
    const float* a2row = DUAL ? (A2 + (size_t)row * DIM + wv * 256) : nullptr;
    const float* wrow  = W + (size_t)o * DIM + wv * 256;
    f32x4 acc = {0.f, 0.f, 0.f, 0.f};
#pragma unroll 4
    for (int k = 0; k < 256; k += 4) {
        f32x4 a = *(const f32x4*)(arow + k);
        if (DUAL) a += *(const f32x4*)(a2row + k);
        f32x4 w = *(const f32x4*)(wrow + k);
        acc += a * w;
    }
    __shared__ float red[4][64];
    red[wv][lane] = acc[0] + acc[1] + acc[2] + acc[3];
    __syncthreads();
    int t = threadIdx.x;
    if (t < 64)
        O[(size_t)b * DIM + oc * 64 + t] = red[0][t] + red[1][t] + red[2][t] + red[3][t];
}

extern "C" void kernel_launch(void* const* d_in, const int* in_sizes, int n_in,
                              void* d_out, int out_size, void* d_ws, size_t ws_size,
                              hipStream_t stream) {
    const float* query  = (const float*)d_in[0];
    const float* keys   = (const float*)d_in[1];
    const float* values = (const float*)d_in[2];
    const float* Wq = (const float*)d_in[3];
    const float* Wk = (const float*)d_in[4];
    const float* Wv = (const float*)d_in[5];
    const float* Wo = (const float*)d_in[6];
    float* out = (float*)d_out;

    char* ws = (char*)d_ws;
    short*  u    = (short*)(ws + 0);                        // 1 MB
    float*  dotb = (float*)(ws + (1 << 20));                // 4 MB [b][s][h]
    float*  z0   = (float*)(ws + (5 << 20));                // 2 MB
    float*  z1   = (float*)(ws + (7 << 20));                // 2 MB
    float*  attn = (float*)(ws + (9 << 20));                // 128 KB
    float2* part = (float2*)(ws + (9 << 20) + (128 << 10)); // 128 KB

    hipLaunchKernelGGL(k_qu,          dim3(512),  dim3(256), 0, stream, query, Wq, Wk, u);
    hipLaunchKernelGGL(k_dot,         dim3(1024), dim3(256), 0, stream, keys, u, dotb, part);
    hipLaunchKernelGGL(k_z,           dim3(1024), dim3(256), 0, stream, values, dotb, part, z0);
    hipLaunchKernelGGL(k_gemm<true>,  dim3(512),  dim3(256), 0, stream, z0, z1, Wv, attn, 16, 1);
    hipLaunchKernelGGL(k_gemm<false>, dim3(512),  dim3(256), 0, stream, attn, nullptr, Wo, out, 1, 0);
}

// Round 5
// 207.876 us; speedup vs baseline: 1.1036x; 1.1036x over previous
//
#include <hip/hip_runtime.h>

#define SL  2048
#define BSZ 32
#define DIM 1024
#define NH  16
#define HD  64

typedef __attribute__((ext_vector_type(4))) float f32x4;
typedef __attribute__((ext_vector_type(8))) short s16x8;

static __device__ __forceinline__ short f2bf(float f) {
    union { float f; unsigned u; } v; v.f = f;
    unsigned r = (v.u + 0x7fffu + ((v.u >> 16) & 1u)) >> 16;  // RNE
    return (short)r;
}

// Fused: qp_slice[i] = query[b].Wq[h*64+i]  (i<64), then
// u[b][h][j] = 0.125 * sum_i qp_slice[i] * Wk[h*64+i][j]  (bf16)
__global__ __launch_bounds__(256) void k_qu(const float* __restrict__ query,
                                            const float* __restrict__ Wq,
                                            const float* __restrict__ Wk,
                                            short* __restrict__ u) {
    int b = blockIdx.x & 31;
    int h = blockIdx.x >> 5;
    int t = threadIdx.x;
    __shared__ float red[256];
    __shared__ float sq[HD];
    {   // stage 1: 4 threads per i (k-quarters)
        int i  = t >> 2;
        int kq = t & 3;
        const float* q = query + (size_t)b * DIM + kq * 256;
        const float* w = Wq + (size_t)(h * HD + i) * DIM + kq * 256;
        f32x4 acc = {0.f, 0.f, 0.f, 0.f};
#pragma unroll 4
        for (int k = 0; k < 256; k += 4)
            acc += *(const f32x4*)(q + k) * *(const f32x4*)(w + k);
        red[t] = acc[0] + acc[1] + acc[2] + acc[3];
    }
    __syncthreads();
    if (t < HD) sq[t] = (red[t*4] + red[t*4+1] + red[t*4+2] + red[t*4+3]) * 0.125f;
    __syncthreads();
    // stage 2: each thread owns 4 j columns
    f32x4 acc = {0.f, 0.f, 0.f, 0.f};
    const float* wk = Wk + (size_t)(h * HD) * DIM;
#pragma unroll 8
    for (int i = 0; i < HD; ++i) {
        float s = sq[i];
        const float* row = wk + (size_t)i * DIM;
        acc[0] += s * row[t];
        acc[1] += s * row[t + 256];
        acc[2] += s * row[t + 512];
        acc[3] += s * row[t + 768];
    }
    short* ub = u + ((size_t)(b * NH + h)) * DIM;
    ub[t]       = f2bf(acc[0]);
    ub[t + 256] = f2bf(acc[1]);
    ub[t + 512] = f2bf(acc[2]);
    ub[t + 768] = f2bf(acc[3]);
}

// dot[b][s][h] = keys[s,b,:].u[b,h,:]; also per-block LSE partials (m,l) per h.
__global__ __launch_bounds__(256, 4) void k_dot(const float* __restrict__ keys,
                                                const short* __restrict__ u,
                                                float* __restrict__ dot,
                                                float2* __restrict__ part) {
    int b  = blockIdx.x & 31;
    int st = blockIdx.x >> 5;
    int s0 = st * 64;
    __shared__ short ulds[NH][DIM + 8];
    {
        const uint4* src = (const uint4*)(u + (size_t)b * NH * DIM);
        for (int idx = threadIdx.x; idx < NH * DIM / 8; idx += 256) {
            int row = idx >> 7;
            int col = (idx & 127) * 8;
            *(uint4*)&ulds[row][col] = src[idx];
        }
    }
    __syncthreads();
    int lane = threadIdx.x & 63;
    int wave = threadIdx.x >> 6;
    int lrow = lane & 15;
    int kgrp = lane >> 4;
    f32x4 acc = {0.f, 0.f, 0.f, 0.f};
    const float* ka = keys + ((size_t)(s0 + wave * 16 + lrow) * BSZ + b) * DIM;
#pragma unroll 4
    for (int k0 = 0; k0 < DIM; k0 += 32) {
        int kj = k0 + kgrp * 8;
        s16x8 bf = *(const s16x8*)&ulds[lrow][kj];
        f32x4 a0 = *(const f32x4*)(ka + kj);
        f32x4 a1 = *(const f32x4*)(ka + kj + 4);
        s16x8 af;
        af[0]=f2bf(a0[0]); af[1]=f2bf(a0[1]); af[2]=f2bf(a0[2]); af[3]=f2bf(a0[3]);
        af[4]=f2bf(a1[0]); af[5]=f2bf(a1[1]); af[6]=f2bf(a1[2]); af[7]=f2bf(a1[3]);
        acc = __builtin_amdgcn_mfma_f32_16x16x32_bf16(af, bf, acc, 0, 0, 0);
    }
    size_t obase = ((size_t)b * SL + (s0 + wave * 16 + kgrp * 4)) * NH + lrow;
#pragma unroll
    for (int r = 0; r < 4; ++r)
        dot[obase + (size_t)r * NH] = acc[r];

    __shared__ float mred[4][16], lred[4][16];
    float m = fmaxf(fmaxf(acc[0], acc[1]), fmaxf(acc[2], acc[3]));
    m = fmaxf(m, __shfl_xor(m, 16));
    m = fmaxf(m, __shfl_xor(m, 32));
    if (lane < 16) mred[wave][lrow] = m;
    __syncthreads();
    float mb = fmaxf(fmaxf(mred[0][lrow], mred[1][lrow]),
                     fmaxf(mred[2][lrow], mred[3][lrow]));
    float l = __expf(acc[0]-mb) + __expf(acc[1]-mb) + __expf(acc[2]-mb) + __expf(acc[3]-mb);
    l += __shfl_xor(l, 16);
    l += __shfl_xor(l, 32);
    if (lane < 16) lred[wave][lrow] = l;
    __syncthreads();
    int t = threadIdx.x;
    if (t < 16) {
        float mbb = fmaxf(fmaxf(mred[0][t], mred[1][t]), fmaxf(mred[2][t], mred[3][t]));
        float lb  = lred[0][t] + lred[1][t] + lred[2][t] + lred[3][t];
        part[((size_t)b * 32 + st) * 16 + t] = make_float2(mbb, lb);
    }
}

// zp[sh][b][h][j] = sum_{s in half} dot*v  -  T[b][h] * sum_{s in half} v
// Inner loop = R3-measured form (scalar broadcast LDS reads, in-phase staging).
__global__ __launch_bounds__(256, 4) void k_z(const float* __restrict__ values,
                                              const float* __restrict__ w,
                                              const float2* __restrict__ part,
                                              float* __restrict__ z) {
    int x  = blockIdx.x;
    int b  = x & 31;
    int jc = (x >> 5) & 15;
    int sh = x >> 9;
    int t  = threadIdx.x;
    int ssub = t >> 4;
    int jq = t & 15;
    int j = jc * 64 + jq * 4;
    int wv = __builtin_amdgcn_readfirstlane(t >> 6);
    int lane = t & 63;

    __shared__ float wlds[128 * 16];        // 8 KB
    __shared__ float Tl[16];
    __shared__ float mred8[8][16], lred8[8][16];
    __shared__ f32x4 redW[4][16][16];       // 16 KB
    __shared__ f32x4 redV[4][16];           // 1 KB

    // low-pressure LSE combine: 128 threads x 4 partials, then 16 combine
    if (t < 128) {
        int h = t & 15, g = t >> 4;          // g in 0..7
        const float2* pb = part + (size_t)b * 32 * 16 + h;
        float2 p0 = pb[(g*4+0)*16], p1 = pb[(g*4+1)*16],
               p2 = pb[(g*4+2)*16], p3 = pb[(g*4+3)*16];
        float M = fmaxf(fmaxf(p0.x, p1.x), fmaxf(p2.x, p3.x));
        float L = p0.y*__expf(p0.x-M) + p1.y*__expf(p1.x-M)
                + p2.y*__expf(p2.x-M) + p3.y*__expf(p3.x-M);
        mred8[g][h] = M; lred8[g][h] = L;
    }
    __syncthreads();
    if (t < 16) {
        float M = mred8[0][t];
#pragma unroll
        for (int g = 1; g < 8; ++g) M = fmaxf(M, mred8[g][t]);
        float L = 0.f;
#pragma unroll
        for (int g = 0; g < 8; ++g) L += lred8[g][t] * __expf(mred8[g][t] - M);
        Tl[t] = M + __logf(L);
    }

    f32x4 acc[NH];
#pragma unroll
    for (int h = 0; h < NH; ++h) acc[h] = (f32x4){0.f,0.f,0.f,0.f};
    f32x4 accV = {0.f,0.f,0.f,0.f};

    const float* vbase = values + (size_t)b * DIM + j;
    const float* wbase = w + ((size_t)b * SL + sh * 1024) * NH;

    for (int ph = 0; ph < 8; ++ph) {
        __syncthreads();
        {
            const f32x4* src = (const f32x4*)(wbase + ph * 128 * NH);
            f32x4* dst = (f32x4*)wlds;
            dst[t]       = src[t];
            dst[t + 256] = src[t + 256];
        }
        __syncthreads();
        int sbase = sh * 1024 + ph * 128;
#pragma unroll 4
        for (int it = 0; it < 8; ++it) {
            int s_loc = it * 16 + ssub;
            f32x4 v = *(const f32x4*)(vbase + (size_t)(sbase + s_loc) * (BSZ * DIM));
            const float* wr = wlds + s_loc * 16;
#pragma unroll
            for (int h = 0; h < NH; ++h) {
                float wh = wr[h];
                acc[h] += v * wh;
            }
            accV += v;
        }
    }

    // reduce across ssub within wave (lanes 16, 32 apart)
#pragma unroll
    for (int h = 0; h < NH; ++h) {
#pragma unroll
        for (int e = 0; e < 4; ++e) {
            float x0 = acc[h][e];
            x0 += __shfl_xor(x0, 16);
            x0 += __shfl_xor(x0, 32);
            acc[h][e] = x0;
        }
    }
#pragma unroll
    for (int e = 0; e < 4; ++e) {
        float x0 = accV[e];
        x0 += __shfl_xor(x0, 16);
        x0 += __shfl_xor(x0, 32);
        accV[e] = x0;
    }
    if (lane < 16) {
#pragma unroll
        for (int h = 0; h < NH; ++h) redW[wv][h][lane] = acc[h];
        redV[wv][lane] = accV;
    }
    __syncthreads();
    int h2 = t >> 4, q = t & 15;
    f32x4 sumW = redW[0][h2][q] + redW[1][h2][q] + redW[2][h2][q] + redW[3][h2][q];
    f32x4 sumV = redV[0][q] + redV[1][q] + redV[2][q] + redV[3][q];
    float Th = Tl[h2];
    f32x4 zv = sumW - Th * sumV;
    float* zp = z + (size_t)sh * (BSZ * NH * DIM);
    *(f32x4*)(zp + ((size_t)(b * NH + h2)) * DIM + jc * 64 + q * 4) = zv;
}

// O[b][o] = dot(A_row(b,o) [+A2_row], W[o][:])
template<bool DUAL>
__global__ __launch_bounds__(256) void k_gemm(const float* __restrict__ A,
                                              const float* __restrict__ A2,
                                              const float* __restrict__ W,
                                              float* __restrict__ O,
                                              int rmul, int hsel) {
    int oc = blockIdx.x & 15;
    int b  = blockIdx.x >> 4;
    int wv = __builtin_amdgcn_readfirstlane(threadIdx.x >> 6);
    int lane = threadIdx.x & 63;
    int o = oc * 64 + lane;
    int row = b * rmul + (hsel ? oc : 0);
    const float* arow  = A + (size_t)row * DIM + wv * 256;
    const float* a2row = DUAL ? (A2 + (size_t)row * DIM + wv * 256) : nullptr;
    const float* wrow  = W + (size_t)o * DIM + wv * 256;
    f32x4 acc = {0.f, 0.f, 0.f, 0.f};
#pragma unroll 4
    for (int k = 0; k < 256; k += 4) {
        f32x4 a = *(const f32x4*)(arow + k);
        if (DUAL) a += *(const f32x4*)(a2row + k);
        f32x4 w = *(const f32x4*)(wrow + k);
        acc += a * w;
    }
    __shared__ float red[4][64];
    red[wv][lane] = acc[0] + acc[1] + acc[2] + acc[3];
    __syncthreads();
    int t = threadIdx.x;
    if (t < 64)
        O[(size_t)b * DIM + oc * 64 + t] = red[0][t] + red[1][t] + red[2][t] + red[3][t];
}

extern "C" void kernel_launch(void* const* d_in, const int* in_sizes, int n_in,
                              void* d_out, int out_size, void* d_ws, size_t ws_size,
                              hipStream_t stream) {
    const float* query  = (const float*)d_in[0];
    const float* keys   = (const float*)d_in[1];
    const float* values = (const float*)d_in[2];
    const float* Wq = (const float*)d_in[3];
    const float* Wk = (const float*)d_in[4];
    const float* Wv = (const float*)d_in[5];
    const float* Wo = (const float*)d_in[6];
    float* out = (float*)d_out;

    char* ws = (char*)d_ws;
    short*  u    = (short*)(ws + 0);                        // 1 MB
    float*  dotb = (float*)(ws + (1 << 20));                // 4 MB [b][s][h]
    float*  z0   = (float*)(ws + (5 << 20));                // 2 MB
    float*  z1   = (float*)(ws + (7 << 20));                // 2 MB
    float*  attn = (float*)(ws + (9 << 20));                // 128 KB
    float2* part = (float2*)(ws + (9 << 20) + (128 << 10)); // 128 KB

    hipLaunchKernelGGL(k_qu,          dim3(512),  dim3(256), 0, stream, query, Wq, Wk, u);
    hipLaunchKernelGGL(k_dot,         dim3(1024), dim3(256), 0, stream, keys, u, dotb, part);
    hipLaunchKernelGGL(k_z,           dim3(1024), dim3(256), 0, stream, values, dotb, part, z0);
    hipLaunchKernelGGL(k_gemm<true>,  dim3(512),  dim3(256), 0, stream, z0, z1, Wv, attn, 16, 1);
    hipLaunchKernelGGL(k_gemm<false>, dim3(512),  dim3(256), 0, stream, attn, nullptr, Wo, out, 1, 0);
}